// Round 9
// baseline (1493.535 us; speedup 1.0000x reference)
//
#include <hip/hip_runtime.h>
#include <hip/hip_bf16.h>

typedef __hip_bfloat16 bf16;
typedef short  bf16x8  __attribute__((ext_vector_type(8)));   // 8 bf16 bit-patterns (4 VGPR)
typedef __bf16 bf16x8n __attribute__((ext_vector_type(8)));   // native type for the builtin
typedef float  f32x4   __attribute__((ext_vector_type(4)));
typedef unsigned long long u64;

constexpr int cN0 = 400000, cN1 = 100000, cN2 = 25000;
constexpr int cNTOT = cN0 + cN1 + cN2;
constexpr int cE0 = 1600000, cE1 = 400000, cE2 = 100000;

static __device__ __forceinline__ float b2f(bf16 x) { return __bfloat162float(x); }
static __device__ __forceinline__ float bflo(unsigned u) { return __uint_as_float(u << 16); }
static __device__ __forceinline__ float bfhi(unsigned u) { return __uint_as_float(u & 0xffff0000u); }

static __device__ __forceinline__ short f2bf_rtne(float f) {
    unsigned u = __float_as_uint(f);
    u = (u + 0x7fffu + ((u >> 16) & 1u)) >> 16;
    return (short)u;
}
// split x ~= hi + lo; 3-term mfma (Ah*Bh + Ah*Bl + Al*Bh) carries ~2^-16 rel err (fp32-class)
static __device__ __forceinline__ void split2(float x, short& h, short& l) {
    unsigned u = __float_as_uint(x);
    h = (short)(u >> 16);
    l = f2bf_rtne(x - __uint_as_float(u & 0xffff0000u));
}

static __device__ __forceinline__ f32x4 mfma16(bf16x8 a, bf16x8 b, f32x4 c) {
    return __builtin_amdgcn_mfma_f32_16x16x32_bf16((bf16x8n)a, (bf16x8n)b, c, 0, 0, 0);
}

// A-fragment (hi/lo) from 8 consecutive fp32 (16B-aligned)
static __device__ __forceinline__ void pack_a8(const float* s8, bf16x8& ah, bf16x8& al) {
    float4 v0 = ((const float4*)s8)[0];
    float4 v1 = ((const float4*)s8)[1];
    float xx[8] = {v0.x, v0.y, v0.z, v0.w, v1.x, v1.y, v1.z, v1.w};
#pragma unroll
    for (int j = 0; j < 8; j++) { short h, l; split2(xx[j], h, l); ah[j] = h; al[j] = l; }
}

// B-fragment (hi/lo) from row-major W[k][n]; k >= kmax zero-padded
static __device__ __forceinline__ void pack_b8(const float* __restrict__ W, int ldn,
                                               int kbase, int col, int kmax,
                                               bf16x8& bh, bf16x8& bl) {
#pragma unroll
    for (int j = 0; j < 8; j++) {
        int k = kbase + j;
        float w = (k < kmax) ? W[(size_t)k * ldn + col] : 0.f;
        short h, l; split2(w, h, l); bh[j] = h; bl[j] = l;
    }
}

// ---------------- Encoder: per-wave 16-node tile, both layers via MFMA ----------------
__global__ __launch_bounds__(256, 2)
void enc_kernel(const float* __restrict__ stat, const float* __restrict__ dyn,
                const float* __restrict__ W1, const float* __restrict__ b1,
                const float* __restrict__ W2, const float* __restrict__ b2,
                const float* __restrict__ pa, bf16* __restrict__ X, int nn)
{
    __shared__ float sF[4][16 * 20];
    __shared__ float sH[4][16 * 68];
    const int lane = threadIdx.x & 63;
    const int slot = threadIdx.x >> 6;
    const int r = lane & 15, g4 = lane >> 4;
    const int wid = blockIdx.x * (blockDim.x >> 6) + slot;
    const int nw  = gridDim.x * (blockDim.x >> 6);

    bf16x8 B1h[4], B1l[4], B2h[2][4], B2l[2][4];
#pragma unroll
    for (int nb = 0; nb < 4; nb++)
        pack_b8(W1, 64, g4 * 8, nb * 16 + r, 16, B1h[nb], B1l[nb]);
#pragma unroll
    for (int s = 0; s < 2; s++)
#pragma unroll
        for (int nb = 0; nb < 4; nb++)
            pack_b8(W2, 64, s * 32 + g4 * 8, nb * 16 + r, 64, B2h[s][nb], B2l[s][nb]);
    float bc1[4], bc2[4];
#pragma unroll
    for (int nb = 0; nb < 4; nb++) { bc1[nb] = b1[nb * 16 + r]; bc2[nb] = b2[nb * 16 + r]; }
    const float a = pa[0];
    float* F = sF[slot];
    float* H = sH[slot];
    const int ntile = (nn + 15) >> 4;

    for (int tt = wid; tt < ntile; tt += nw) {
        const int n0 = tt << 4;
        const int nv = min(16, nn - n0);
        for (int t = lane; t < nv * 6; t += 64)
            F[(t / 6) * 20 + (t % 6)] = stat[(size_t)n0 * 6 + t];
        for (int t = lane; t < nv * 10; t += 64)
            F[(t / 10) * 20 + 6 + (t % 10)] = dyn[(size_t)n0 * 10 + t];
        __builtin_amdgcn_wave_barrier();

        f32x4 C1[4];
#pragma unroll
        for (int nb = 0; nb < 4; nb++) C1[nb] = (f32x4){bc1[nb], bc1[nb], bc1[nb], bc1[nb]};
        bf16x8 ah, al;
        if (g4 < 2) pack_a8(F + r * 20 + g4 * 8, ah, al);
        else        { ah = (bf16x8)(short)0; al = (bf16x8)(short)0; }
#pragma unroll
        for (int nb = 0; nb < 4; nb++) {
            C1[nb] = mfma16(ah, B1h[nb], C1[nb]);
            C1[nb] = mfma16(ah, B1l[nb], C1[nb]);
            C1[nb] = mfma16(al, B1h[nb], C1[nb]);
        }
#pragma unroll
        for (int nb = 0; nb < 4; nb++)
#pragma unroll
            for (int q = 0; q < 4; q++) {
                float v = C1[nb][q];
                v = v > 0.f ? v : a * v;
                H[(g4 * 4 + q) * 68 + nb * 16 + r] = v;
            }
        __builtin_amdgcn_wave_barrier();

        f32x4 C2[4];
#pragma unroll
        for (int nb = 0; nb < 4; nb++) C2[nb] = (f32x4){bc2[nb], bc2[nb], bc2[nb], bc2[nb]};
#pragma unroll
        for (int s = 0; s < 2; s++) {
            bf16x8 a2h, a2l;
            pack_a8(H + r * 68 + s * 32 + g4 * 8, a2h, a2l);
#pragma unroll
            for (int nb = 0; nb < 4; nb++) {
                C2[nb] = mfma16(a2h, B2h[s][nb], C2[nb]);
                C2[nb] = mfma16(a2h, B2l[s][nb], C2[nb]);
                C2[nb] = mfma16(a2l, B2h[s][nb], C2[nb]);
            }
        }
#pragma unroll
        for (int nb = 0; nb < 4; nb++)
#pragma unroll
            for (int q = 0; q < 4; q++) {
                float v = C2[nb][q];
                v = v > 0.f ? v : a * v;
                const int row = g4 * 4 + q;
                if (row < nv)
                    X[(size_t)(n0 + row) * 64 + nb * 16 + r] = __float2bfloat16(v);
            }
        __builtin_amdgcn_wave_barrier();
    }
}

// ---------------- CSR build: ONE packed 64-bit atomic per edge ----------------
__global__ void zdc_kernel(u64* p, int n)
{
    int t = blockIdx.x * 256 + threadIdx.x;
    if (t < n) p[t] = 0ull;
}
__global__ void edge_pack_kernel(const int* __restrict__ dst, const float* __restrict__ ew,
                                 u64* __restrict__ dc, int ne)
{
    int e = blockIdx.x * 256 + threadIdx.x;
    if (e < ne) {
        u64 pk = (1ull << 40) | (u64)(ew[e] * 268435456.f + 0.5f);
        atomicAdd(&dc[dst[e]], pk);
    }
}

// ---- ordered CSR: exclusive prefix scan of unpacked cnt; dinv computed in pass 1 ----
__global__ void scan_blk_kernel(const u64* __restrict__ dc, int* __restrict__ base,
                                int* __restrict__ bsum, float* __restrict__ dinv, int n)
{
    __shared__ int s[256];
    const int tid = threadIdx.x;
    const int t = blockIdx.x * 256 + tid;
    u64 pk = (t < n) ? dc[t] : 0ull;
    int v = (int)(pk >> 40);
    s[tid] = v;
    __syncthreads();
#pragma unroll
    for (int d = 1; d < 256; d <<= 1) {
        int u = (tid >= d) ? s[tid - d] : 0;
        __syncthreads();
        s[tid] += u;
        __syncthreads();
    }
    if (t < n) {
        base[t] = s[tid] - v;
        const float deg = 1.f + (float)(pk & ((1ull << 40) - 1ull)) * (1.f / 268435456.f);
        dinv[t] = rsqrtf(deg);
    }
    if (tid == 255) bsum[blockIdx.x] = s[255];
}
__global__ void scan_top_kernel(int* __restrict__ bsum, int nb)
{
    __shared__ int s[256];
    __shared__ int carry;
    const int tid = threadIdx.x;
    if (tid == 0) carry = 0;
    __syncthreads();
    for (int c0 = 0; c0 < nb; c0 += 256) {
        const int t = c0 + tid;
        int v = (t < nb) ? bsum[t] : 0;
        s[tid] = v;
        __syncthreads();
#pragma unroll
        for (int d = 1; d < 256; d <<= 1) {
            int u = (tid >= d) ? s[tid - d] : 0;
            __syncthreads();
            s[tid] += u;
            __syncthreads();
        }
        if (t < nb) bsum[t] = carry + s[tid] - v;
        __syncthreads();
        if (tid == 255) carry += s[255];
        __syncthreads();
    }
}
__global__ void scan_add_kernel(int* __restrict__ base, const int* __restrict__ bsum,
                                int* __restrict__ cur, int n)
{
    const int t = blockIdx.x * 256 + threadIdx.x;
    if (t < n) { int b = base[t] + bsum[blockIdx.x]; base[t] = b; cur[t] = b; }
}

__global__ void grab_kernel(const int* __restrict__ cnt, int* __restrict__ base,
                            int* __restrict__ cur, int* __restrict__ gc, int n)
{
    int t = blockIdx.x * 256 + threadIdx.x;
    if (t < n) { int b = atomicAdd(gc, cnt[t]); base[t] = b; cur[t] = b; }
}
__global__ void fill_edge_kernel(const int* __restrict__ src, const int* __restrict__ dst,
                                 const float* __restrict__ ew, const float* __restrict__ dinv,
                                 int* __restrict__ cur, int* __restrict__ srcp,
                                 bf16* __restrict__ normp, int ne)
{
    int e = blockIdx.x * 256 + threadIdx.x;
    if (e >= ne) return;
    int d = dst[e], s = src[e];
    int pos = atomicAdd(&cur[d], 1);
    srcp[pos]  = s;
    normp[pos] = __float2bfloat16(dinv[s] * ew[e] * dinv[d]);
}
__global__ void zint2_kernel(int* __restrict__ p, int* __restrict__ gc, int n)
{
    int t = blockIdx.x * 256 + threadIdx.x;
    if (t < n) p[t] = 0;
    if (t == 0) gc[0] = 0;
}
__global__ void cnt_idx_kernel(const int* __restrict__ idx, int* __restrict__ cnt, int n)
{
    int j = blockIdx.x * 256 + threadIdx.x;
    if (j < n) atomicAdd(&cnt[idx[j]], 1);
}
__global__ void fill_idx_kernel(const int* __restrict__ idx, int* __restrict__ cur,
                                int* __restrict__ jp, int n)
{
    int j = blockIdx.x * 256 + threadIdx.x;
    if (j >= n) return;
    int pos = atomicAdd(&cur[idx[j]], 1);
    jp[pos] = j;
}

// ---- Fused conv v7: 512-thread blocks, 8 waves share ONE LDS W-mirror
//      (LDS/block 51.4 KB -> 3 blocks/CU -> 24 waves/CU = 75% occupancy ceiling);
//      edge-walk/flush/GEMM logic R4-proven, unchanged ----
__global__ __launch_bounds__(512, 6)
void fused_conv_kernel(const int* __restrict__ base,
                       const int* __restrict__ srcp, const bf16* __restrict__ normp,
                       const bf16* __restrict__ h_in, bf16* __restrict__ h_out,
                       const float* __restrict__ dinv,
                       const float* __restrict__ W, int woff,
                       const float* __restrict__ bias, int boff,
                       const float* __restrict__ filt, int foff,
                       int first, int store_h, float* __restrict__ acc,
                       int nn, int ne)
{
    __shared__ float sb[8][16 * 68];     // per-wave g-tile [16 nodes][64 pad 68] (34816 B)
    __shared__ unsigned sW[64 * 65];     // W fragments, lane-major stride-65 u32 (16640 B)
    const int lane = threadIdx.x & 63;
    const int slot = threadIdx.x >> 6;
    const int r = lane & 15, g4 = lane >> 4;
    const int wid  = blockIdx.x * (blockDim.x >> 6) + slot;
    const int nw   = gridDim.x * (blockDim.x >> 6);

    // wave 0 packs W once for the whole block
    if (slot == 0) {
        unsigned* dstw = sW + lane * 65;
#pragma unroll
        for (int s = 0; s < 2; s++)
#pragma unroll
            for (int nb = 0; nb < 4; nb++) {
                bf16x8 bh, bl;
                pack_b8(W + woff, 64, s * 32 + g4 * 8, nb * 16 + r, 64, bh, bl);
                const int f = s * 4 + nb;
                uint4 uh = *(uint4*)&bh;
                uint4 ul = *(uint4*)&bl;
                dstw[f * 4 + 0] = uh.x; dstw[f * 4 + 1] = uh.y;
                dstw[f * 4 + 2] = uh.z; dstw[f * 4 + 3] = uh.w;
                dstw[32 + f * 4 + 0] = ul.x; dstw[32 + f * 4 + 1] = ul.y;
                dstw[32 + f * 4 + 2] = ul.z; dstw[32 + f * 4 + 3] = ul.w;
            }
    }
    __syncthreads();

    float bc[4];
#pragma unroll
    for (int nb = 0; nb < 4; nb++) bc[nb] = bias[boff + nb * 16 + r];
    const float fc = filt[foff];
    float* sbrow = sb[slot];
    const unsigned* myW = sW + lane * 65;
    const int ngrp = (nn + 15) >> 4;

    for (int grp = wid; grp < ngrp; grp += nw) {
        const int n0 = grp << 4;
        int rpl = 0;
        if (lane <= 16) rpl = (n0 + lane < nn) ? base[n0 + lane] : ne;
        // group g4 owns nodes [b4, b4+4); its 5 rowptrs hoisted to regs (full-exec shfl)
        const int b4 = g4 << 2;
        const int q0 = __shfl(rpl, b4);
        const int q1 = __shfl(rpl, b4 + 1);
        const int q2 = __shfl(rpl, b4 + 2);
        const int q3 = __shfl(rpl, b4 + 3);
        const int q4 = __shfl(rpl, b4 + 4);

        int   curl  = 0;                 // local node 0..3; row = b4+curl, single writer
        int   rnext = q1;
        float g0 = 0.f, g1 = 0.f, g2 = 0.f, g3 = 0.f;   // features 4r..4r+3
        auto flush = [&]() {             // plain b128 write; rnext from regs (no shfl)
            *(float4*)(sbrow + (b4 + curl) * 68 + (r << 2)) = make_float4(g0, g1, g2, g3);
            g0 = g1 = g2 = g3 = 0.f;
            curl++;
            rnext = (curl == 1) ? q2 : (curl == 2) ? q3 : (curl == 3) ? q4 : 0x7fffffff;
        };

        for (int eb = q0; eb < q4; eb += 16) {
            const int ei_ = min(eb + r, q4 - 1);           // clamped batch of (src, norm)
            int   sv = srcp[ei_];
            float nv = (eb + r < q4) ? b2f(normp[ei_]) : 0.f;
#pragma unroll
            for (int t = 0; t < 16; t += 8) {              // 8 edges in flight per group
                const int bidx = (g4 << 4) + t;
                int ss[8]; float mm[8]; uint2 pp[8];
#pragma unroll
                for (int j = 0; j < 8; j++) {
                    ss[j] = __shfl(sv, bidx + j);
                    mm[j] = __shfl(nv, bidx + j);
                }
#pragma unroll
                for (int j = 0; j < 8; j++)
                    pp[j] = *(const uint2*)(h_in + ((size_t)ss[j] << 6) + (r << 2));
#pragma unroll
                for (int j = 0; j < 8; j++) {              // consume + boundary flush
                    while (eb + t + j >= rnext) flush();   // flush-before-accumulate (v3-proven)
                    g0 += mm[j] * bflo(pp[j].x); g1 += mm[j] * bfhi(pp[j].x);
                    g2 += mm[j] * bflo(pp[j].y); g3 += mm[j] * bfhi(pp[j].y);
                }
            }
        }
        while (curl < 4) flush();        // remaining partial + zero rows (every row written once)
        __builtin_amdgcn_wave_barrier();

        // self-loop term, vectorized: lane (r,g4) -> node r, features [g4*16, g4*16+16)
        {
            const int node = n0 + r;
            const int ncl = min(node, nn - 1);
            float di = dinv[ncl];
            di = (node < nn) ? di * di : 0.f;
            float* rowp = sbrow + r * 68 + (g4 << 4);
#pragma unroll
            for (int hh = 0; hh < 2; hh++) {
                uint4 hv = *(const uint4*)(h_in + ((size_t)ncl << 6) + (g4 << 4) + hh * 8);
                float4 f0 = *(float4*)(rowp + hh * 8);
                float4 f1 = *(float4*)(rowp + hh * 8 + 4);
                f0.x += di * bflo(hv.x); f0.y += di * bfhi(hv.x);
                f0.z += di * bflo(hv.y); f0.w += di * bfhi(hv.y);
                f1.x += di * bflo(hv.z); f1.y += di * bfhi(hv.z);
                f1.z += di * bflo(hv.w); f1.w += di * bfhi(hv.w);
                *(float4*)(rowp + hh * 8)     = f0;
                *(float4*)(rowp + hh * 8 + 4) = f1;
            }
        }
        __builtin_amdgcn_wave_barrier();

        const int nv16 = min(16, nn - n0);
        f32x4 C[4];
#pragma unroll
        for (int nb = 0; nb < 4; nb++) C[nb] = (f32x4){bc[nb], bc[nb], bc[nb], bc[nb]};
#pragma unroll
        for (int s = 0; s < 2; s++) {
            bf16x8 ah, al;
            pack_a8(sbrow + r * 68 + s * 32 + g4 * 8, ah, al);
#pragma unroll
            for (int nb = 0; nb < 4; nb++) {
                const int f = s * 4 + nb;
                uint4 uh = *(const uint4*)(myW + f * 4);        // ds_read_b128, 2-way = free
                uint4 ul = *(const uint4*)(myW + 32 + f * 4);
                bf16x8 bh = *(bf16x8*)&uh;
                bf16x8 bl = *(bf16x8*)&ul;
                C[nb] = mfma16(ah, bh, C[nb]);
                C[nb] = mfma16(ah, bl, C[nb]);
                C[nb] = mfma16(al, bh, C[nb]);
            }
        }
#pragma unroll
        for (int nb = 0; nb < 4; nb++)
#pragma unroll
            for (int q = 0; q < 4; q++) {
                const int row = g4 * 4 + q;
                if (row < nv16) {
                    const float sv_ = C[nb][q];
                    const float e = __expf(2.f * sv_);
                    const float h = 1.f - 2.f * __builtin_amdgcn_rcpf(e + 1.f);
                    const size_t ai = (size_t)(n0 + row) * 64 + nb * 16 + r;
                    if (store_h) h_out[ai] = __float2bfloat16(h);
                    acc[ai] = (first ? 0.f : acc[ai]) + fc * h;
                }
            }
        __builtin_amdgcn_wave_barrier();
    }
}

// ---------------- pooling gather (R7-proven) ----------------
__global__ void pool_gather_kernel(const int* __restrict__ base, const int* __restrict__ cnt,
                                   const int* __restrict__ jp, const float* __restrict__ accc,
                                   float* __restrict__ fin, int nn)
{
    const int lane = threadIdx.x & 63;
    const int n = blockIdx.x * (blockDim.x >> 6) + (threadIdx.x >> 6);
    if (n >= nn) return;
    const int m = cnt[n];
    if (m == 0) return;
    const int bs = base[n];
    float s = 0.f;
    for (int t = bs; t < bs + m; t++) {
        int j = jp[t];
        s += accc[(size_t)j * 64 + lane];
    }
    fin[(size_t)n * 64 + lane] += s / (float)m;
}

// ---------------- Decoder: layer1 MFMA, layer2 shuffle-reduce ----------------
__global__ __launch_bounds__(256, 3)
void dec_kernel(const float* __restrict__ fin,
                const float* __restrict__ W1, const float* __restrict__ b1,
                const float* __restrict__ W2, const float* __restrict__ b2,
                const float* __restrict__ pa, float* __restrict__ out, int nn)
{
    const int lane = threadIdx.x & 63;
    const int r = lane & 15, g4 = lane >> 4;
    const int wid = blockIdx.x * (blockDim.x >> 6) + (threadIdx.x >> 6);
    const int nw  = gridDim.x * (blockDim.x >> 6);

    bf16x8 Wh[2][4], Wl[2][4];
#pragma unroll
    for (int s = 0; s < 2; s++)
#pragma unroll
        for (int nb = 0; nb < 4; nb++)
            pack_b8(W1, 64, s * 32 + g4 * 8, nb * 16 + r, 64, Wh[s][nb], Wl[s][nb]);
    float bc[4], w20[4], w21[4];
#pragma unroll
    for (int nb = 0; nb < 4; nb++) {
        bc[nb]  = b1[nb * 16 + r];
        w20[nb] = W2[(nb * 16 + r) * 2 + 0];
        w21[nb] = W2[(nb * 16 + r) * 2 + 1];
    }
    const float bb20 = b2[0], bb21 = b2[1];
    const float a = pa[0];
    const int ntile = (nn + 15) >> 4;

    for (int tt = wid; tt < ntile; tt += nw) {
        const int n0 = tt << 4;
        f32x4 C[4];
#pragma unroll
        for (int nb = 0; nb < 4; nb++) C[nb] = (f32x4){bc[nb], bc[nb], bc[nb], bc[nb]};
#pragma unroll
        for (int s = 0; s < 2; s++) {
            bf16x8 ah, al;
            pack_a8(fin + (size_t)(n0 + r) * 64 + s * 32 + g4 * 8, ah, al);
#pragma unroll
            for (int nb = 0; nb < 4; nb++) {
                C[nb] = mfma16(ah, Wh[s][nb], C[nb]);
                C[nb] = mfma16(ah, Wl[s][nb], C[nb]);
                C[nb] = mfma16(al, Wh[s][nb], C[nb]);
            }
        }
#pragma unroll
        for (int q = 0; q < 4; q++) {
            float p0 = 0.f, p1 = 0.f;
#pragma unroll
            for (int nb = 0; nb < 4; nb++) {
                float y = C[nb][q];
                y = y > 0.f ? y : a * y;
                p0 += y * w20[nb]; p1 += y * w21[nb];
            }
            p0 += __shfl_xor(p0, 1); p1 += __shfl_xor(p1, 1);
            p0 += __shfl_xor(p0, 2); p1 += __shfl_xor(p1, 2);
            p0 += __shfl_xor(p0, 4); p1 += __shfl_xor(p1, 4);
            p0 += __shfl_xor(p0, 8); p1 += __shfl_xor(p1, 8);
            if (r == 0) {
                const int node = n0 + g4 * 4 + q;
                if (node < nn) {
                    float o0 = p0 + bb20; o0 = o0 > 0.f ? o0 : a * o0;
                    float o1 = p1 + bb21; o1 = o1 > 0.f ? o1 : a * o1;
                    ((float2*)out)[node] = make_float2(o0, o1);
                }
            }
        }
    }
}

extern "C" void kernel_launch(void* const* d_in, const int* in_sizes, int n_in,
                              void* d_out, int out_size, void* d_ws, size_t ws_size,
                              hipStream_t stream)
{
    const float* stat = (const float*)d_in[0];
    const float* dyn  = (const float*)d_in[1];
    const int*   ei[3]   = {(const int*)d_in[2], (const int*)d_in[4], (const int*)d_in[6]};
    const float* ea[3]   = {(const float*)d_in[3], (const float*)d_in[5], (const float*)d_in[7]};
    const int*   pidx[2] = {(const int*)d_in[8], (const int*)d_in[9]};
    const float* encW1 = (const float*)d_in[10]; const float* encb1 = (const float*)d_in[11];
    const float* encW2 = (const float*)d_in[12]; const float* encb2 = (const float*)d_in[13];
    const float* encpa = (const float*)d_in[14];
    const float* gW    = (const float*)d_in[15]; const float* gbias = (const float*)d_in[16];
    const float* filt  = (const float*)d_in[17];
    const float* dW1   = (const float*)d_in[18]; const float* db1   = (const float*)d_in[19];
    const float* dW2   = (const float*)d_in[20]; const float* db2   = (const float*)d_in[21];
    const float* dpa   = (const float*)d_in[22];

    auto al = [](size_t x) { return (x + 255) & ~(size_t)255; };
    char* w = (char*)d_ws;
    size_t off = 0;
    bf16* X    = (bf16*)(w + off); off += al((size_t)cNTOT * 64 * 2);   // 67.2 MB
    bf16* HB   = (bf16*)(w + off); off += al((size_t)cN0 * 64 * 2);     // 51.2 MB
    float* FIN = (float*)(w + off); off += al((size_t)cN0 * 64 * 4);    // 102.4 MB
    float* ACCC= (float*)(w + off); off += al((size_t)cN1 * 64 * 4);    // 25.6 MB
    float* DINV= (float*)(w + off); off += al((size_t)cN0 * 4);
    int* CNTI  = (int*)(w + off);  off += al((size_t)cN0 * 4);
    int* BASE  = (int*)(w + off);  off += al((size_t)cN0 * 4);
    int* CUR   = (int*)(w + off);  off += al((size_t)cN0 * 4);
    int* SRCP  = (int*)(w + off);  off += al((size_t)cE0 * 4);
    bf16* NORMP= (bf16*)(w + off); off += al((size_t)cE0 * 2);
    int* JP    = (int*)(w + off);  off += al((size_t)cN1 * 4);
    int* GC    = (int*)(w + off);  off += 256;
    int* BSUM  = (int*)(w + off);  off += al((size_t)2048 * 4);         // == R4's proven ~263 MB
    // DC (u64[cN0] = 3.2 MB) ALIASES ACCC (25.6 MB): DC is consumed by scan_blk before any
    // conv writes ACCC (first=1 full overwrite), and each scale's pool_gather drains ACCC
    // before the next scale's zdc. Stream-ordered, zero extra workspace.
    u64* DC    = (u64*)ACCC;

    const int Ns[3]  = {cN0, cN1, cN2};
    const int Es[3]  = {cE0, cE1, cE2};
    const int ptr[3] = {0, cN0, cN0 + cN1};
#define NB(x) (((x) + 255) / 256)

    enc_kernel<<<4096, 256, 0, stream>>>(stat, dyn, encW1, encb1, encW2, encb2, encpa, X, cNTOT);

    for (int i = 0; i < 3; i++) {
        const int* srcp_in = ei[i];
        const int* dstp    = ei[i] + Es[i];
        zdc_kernel      <<<NB(Ns[i]), 256, 0, stream>>>(DC, Ns[i]);
        edge_pack_kernel<<<NB(Es[i]), 256, 0, stream>>>(dstp, ea[i], DC, Es[i]);
        scan_blk_kernel <<<NB(Ns[i]), 256, 0, stream>>>(DC, BASE, BSUM, DINV, Ns[i]);
        scan_top_kernel <<<1, 256, 0, stream>>>(BSUM, NB(Ns[i]));
        scan_add_kernel <<<NB(Ns[i]), 256, 0, stream>>>(BASE, BSUM, CUR, Ns[i]);
        fill_edge_kernel<<<NB(Es[i]), 256, 0, stream>>>(srcp_in, dstp, ea[i], DINV, CUR, SRCP, NORMP, Es[i]);

        bf16* ping = X + (size_t)ptr[i] * 64;
        bf16* pong = HB;
        float* acc_i = (i == 0) ? FIN : ACCC;
        const int ngrp = (Ns[i] + 15) / 16;
        const int cblk = max(1, min(3072, (ngrp + 7) / 8));
        for (int k = 0; k < 3; k++) {
            bf16* hin  = (k & 1) ? pong : ping;
            bf16* hout = (k & 1) ? ping : pong;
            fused_conv_kernel<<<cblk, 512, 0, stream>>>(BASE, SRCP, NORMP,
                hin, hout, DINV, gW, i * 4096, gbias, i * 64,
                filt, i * 3 + k, (k == 0) ? 1 : 0, (k < 2) ? 1 : 0, acc_i, Ns[i], Es[i]);
        }
        if (i >= 1) {
            int nj = (i == 1) ? cN1 : cN2;
            const int* pp = pidx[i - 1];
            zint2_kernel   <<<NB(cN0), 256, 0, stream>>>(CNTI, GC, cN0);
            cnt_idx_kernel <<<NB(nj), 256, 0, stream>>>(pp, CNTI, nj);
            grab_kernel    <<<NB(cN0), 256, 0, stream>>>(CNTI, BASE, CUR, GC, cN0);
            fill_idx_kernel<<<NB(nj), 256, 0, stream>>>(pp, CUR, JP, nj);
            pool_gather_kernel<<<(cN0 + 3) / 4, 256, 0, stream>>>(BASE, CNTI, JP, ACCC, FIN, cN0);
        }
    }
    dec_kernel<<<4096, 256, 0, stream>>>(FIN, dW1, db1, dW2, db2, dpa, (float*)d_out, cN0);
#undef NB
}

// Round 10
// 1260.392 us; speedup vs baseline: 1.1850x; 1.1850x over previous
//
#include <hip/hip_runtime.h>
#include <hip/hip_bf16.h>

typedef __hip_bfloat16 bf16;
typedef short  bf16x8  __attribute__((ext_vector_type(8)));   // 8 bf16 bit-patterns (4 VGPR)
typedef __bf16 bf16x8n __attribute__((ext_vector_type(8)));   // native type for the builtin
typedef float  f32x4   __attribute__((ext_vector_type(4)));
typedef unsigned long long u64;

constexpr int cN0 = 400000, cN1 = 100000, cN2 = 25000;
constexpr int cNTOT = cN0 + cN1 + cN2;
constexpr int cE0 = 1600000, cE1 = 400000, cE2 = 100000;

static __device__ __forceinline__ float b2f(bf16 x) { return __bfloat162float(x); }
static __device__ __forceinline__ float bflo(unsigned u) { return __uint_as_float(u << 16); }
static __device__ __forceinline__ float bfhi(unsigned u) { return __uint_as_float(u & 0xffff0000u); }

static __device__ __forceinline__ short f2bf_rtne(float f) {
    unsigned u = __float_as_uint(f);
    u = (u + 0x7fffu + ((u >> 16) & 1u)) >> 16;
    return (short)u;
}
// split x ~= hi + lo; 3-term mfma (Ah*Bh + Ah*Bl + Al*Bh) carries ~2^-16 rel err (fp32-class)
static __device__ __forceinline__ void split2(float x, short& h, short& l) {
    unsigned u = __float_as_uint(x);
    h = (short)(u >> 16);
    l = f2bf_rtne(x - __uint_as_float(u & 0xffff0000u));
}

static __device__ __forceinline__ f32x4 mfma16(bf16x8 a, bf16x8 b, f32x4 c) {
    return __builtin_amdgcn_mfma_f32_16x16x32_bf16((bf16x8n)a, (bf16x8n)b, c, 0, 0, 0);
}

// A-fragment (hi/lo) from 8 consecutive fp32 (16B-aligned)
static __device__ __forceinline__ void pack_a8(const float* s8, bf16x8& ah, bf16x8& al) {
    float4 v0 = ((const float4*)s8)[0];
    float4 v1 = ((const float4*)s8)[1];
    float xx[8] = {v0.x, v0.y, v0.z, v0.w, v1.x, v1.y, v1.z, v1.w};
#pragma unroll
    for (int j = 0; j < 8; j++) { short h, l; split2(xx[j], h, l); ah[j] = h; al[j] = l; }
}

// B-fragment (hi/lo) from row-major W[k][n]; k >= kmax zero-padded
static __device__ __forceinline__ void pack_b8(const float* __restrict__ W, int ldn,
                                               int kbase, int col, int kmax,
                                               bf16x8& bh, bf16x8& bl) {
#pragma unroll
    for (int j = 0; j < 8; j++) {
        int k = kbase + j;
        float w = (k < kmax) ? W[(size_t)k * ldn + col] : 0.f;
        short h, l; split2(w, h, l); bh[j] = h; bl[j] = l;
    }
}

// ---------------- Encoder: per-wave 16-node tile, both layers via MFMA ----------------
__global__ __launch_bounds__(256, 2)
void enc_kernel(const float* __restrict__ stat, const float* __restrict__ dyn,
                const float* __restrict__ W1, const float* __restrict__ b1,
                const float* __restrict__ W2, const float* __restrict__ b2,
                const float* __restrict__ pa, bf16* __restrict__ X, int nn)
{
    __shared__ float sF[4][16 * 20];
    __shared__ float sH[4][16 * 68];
    const int lane = threadIdx.x & 63;
    const int slot = threadIdx.x >> 6;
    const int r = lane & 15, g4 = lane >> 4;
    const int wid = blockIdx.x * (blockDim.x >> 6) + slot;
    const int nw  = gridDim.x * (blockDim.x >> 6);

    bf16x8 B1h[4], B1l[4], B2h[2][4], B2l[2][4];
#pragma unroll
    for (int nb = 0; nb < 4; nb++)
        pack_b8(W1, 64, g4 * 8, nb * 16 + r, 16, B1h[nb], B1l[nb]);
#pragma unroll
    for (int s = 0; s < 2; s++)
#pragma unroll
        for (int nb = 0; nb < 4; nb++)
            pack_b8(W2, 64, s * 32 + g4 * 8, nb * 16 + r, 64, B2h[s][nb], B2l[s][nb]);
    float bc1[4], bc2[4];
#pragma unroll
    for (int nb = 0; nb < 4; nb++) { bc1[nb] = b1[nb * 16 + r]; bc2[nb] = b2[nb * 16 + r]; }
    const float a = pa[0];
    float* F = sF[slot];
    float* H = sH[slot];
    const int ntile = (nn + 15) >> 4;

    for (int tt = wid; tt < ntile; tt += nw) {
        const int n0 = tt << 4;
        const int nv = min(16, nn - n0);
        for (int t = lane; t < nv * 6; t += 64)
            F[(t / 6) * 20 + (t % 6)] = stat[(size_t)n0 * 6 + t];
        for (int t = lane; t < nv * 10; t += 64)
            F[(t / 10) * 20 + 6 + (t % 10)] = dyn[(size_t)n0 * 10 + t];
        __builtin_amdgcn_wave_barrier();

        f32x4 C1[4];
#pragma unroll
        for (int nb = 0; nb < 4; nb++) C1[nb] = (f32x4){bc1[nb], bc1[nb], bc1[nb], bc1[nb]};
        bf16x8 ah, al;
        if (g4 < 2) pack_a8(F + r * 20 + g4 * 8, ah, al);
        else        { ah = (bf16x8)(short)0; al = (bf16x8)(short)0; }
#pragma unroll
        for (int nb = 0; nb < 4; nb++) {
            C1[nb] = mfma16(ah, B1h[nb], C1[nb]);
            C1[nb] = mfma16(ah, B1l[nb], C1[nb]);
            C1[nb] = mfma16(al, B1h[nb], C1[nb]);
        }
#pragma unroll
        for (int nb = 0; nb < 4; nb++)
#pragma unroll
            for (int q = 0; q < 4; q++) {
                float v = C1[nb][q];
                v = v > 0.f ? v : a * v;
                H[(g4 * 4 + q) * 68 + nb * 16 + r] = v;
            }
        __builtin_amdgcn_wave_barrier();

        f32x4 C2[4];
#pragma unroll
        for (int nb = 0; nb < 4; nb++) C2[nb] = (f32x4){bc2[nb], bc2[nb], bc2[nb], bc2[nb]};
#pragma unroll
        for (int s = 0; s < 2; s++) {
            bf16x8 a2h, a2l;
            pack_a8(H + r * 68 + s * 32 + g4 * 8, a2h, a2l);
#pragma unroll
            for (int nb = 0; nb < 4; nb++) {
                C2[nb] = mfma16(a2h, B2h[s][nb], C2[nb]);
                C2[nb] = mfma16(a2h, B2l[s][nb], C2[nb]);
                C2[nb] = mfma16(a2l, B2h[s][nb], C2[nb]);
            }
        }
#pragma unroll
        for (int nb = 0; nb < 4; nb++)
#pragma unroll
            for (int q = 0; q < 4; q++) {
                float v = C2[nb][q];
                v = v > 0.f ? v : a * v;
                const int row = g4 * 4 + q;
                if (row < nv)
                    X[(size_t)(n0 + row) * 64 + nb * 16 + r] = __float2bfloat16(v);
            }
        __builtin_amdgcn_wave_barrier();
    }
}

// ---------------- CSR build: ONE packed 64-bit atomic per edge ----------------
__global__ void zdc_kernel(u64* p, int n)
{
    int t = blockIdx.x * 256 + threadIdx.x;
    if (t < n) p[t] = 0ull;
}
__global__ void edge_pack_kernel(const int* __restrict__ dst, const float* __restrict__ ew,
                                 u64* __restrict__ dc, int ne)
{
    int e = blockIdx.x * 256 + threadIdx.x;
    if (e < ne) {
        u64 pk = (1ull << 40) | (u64)(ew[e] * 268435456.f + 0.5f);
        atomicAdd(&dc[dst[e]], pk);
    }
}

// ---- ordered CSR: exclusive prefix scan of unpacked cnt; dinv computed in pass 1 ----
__global__ void scan_blk_kernel(const u64* __restrict__ dc, int* __restrict__ base,
                                int* __restrict__ bsum, float* __restrict__ dinv, int n)
{
    __shared__ int s[256];
    const int tid = threadIdx.x;
    const int t = blockIdx.x * 256 + tid;
    u64 pk = (t < n) ? dc[t] : 0ull;
    int v = (int)(pk >> 40);
    s[tid] = v;
    __syncthreads();
#pragma unroll
    for (int d = 1; d < 256; d <<= 1) {
        int u = (tid >= d) ? s[tid - d] : 0;
        __syncthreads();
        s[tid] += u;
        __syncthreads();
    }
    if (t < n) {
        base[t] = s[tid] - v;
        const float deg = 1.f + (float)(pk & ((1ull << 40) - 1ull)) * (1.f / 268435456.f);
        dinv[t] = rsqrtf(deg);
    }
    if (tid == 255) bsum[blockIdx.x] = s[255];
}
__global__ void scan_top_kernel(int* __restrict__ bsum, int nb)
{
    __shared__ int s[256];
    __shared__ int carry;
    const int tid = threadIdx.x;
    if (tid == 0) carry = 0;
    __syncthreads();
    for (int c0 = 0; c0 < nb; c0 += 256) {
        const int t = c0 + tid;
        int v = (t < nb) ? bsum[t] : 0;
        s[tid] = v;
        __syncthreads();
#pragma unroll
        for (int d = 1; d < 256; d <<= 1) {
            int u = (tid >= d) ? s[tid - d] : 0;
            __syncthreads();
            s[tid] += u;
            __syncthreads();
        }
        if (t < nb) bsum[t] = carry + s[tid] - v;
        __syncthreads();
        if (tid == 255) carry += s[255];
        __syncthreads();
    }
}
__global__ void scan_add_kernel(int* __restrict__ base, const int* __restrict__ bsum,
                                int* __restrict__ cur, int n)
{
    const int t = blockIdx.x * 256 + threadIdx.x;
    if (t < n) { int b = base[t] + bsum[blockIdx.x]; base[t] = b; cur[t] = b; }
}

__global__ void grab_kernel(const int* __restrict__ cnt, int* __restrict__ base,
                            int* __restrict__ cur, int* __restrict__ gc, int n)
{
    int t = blockIdx.x * 256 + threadIdx.x;
    if (t < n) { int b = atomicAdd(gc, cnt[t]); base[t] = b; cur[t] = b; }
}
__global__ void fill_edge_kernel(const int* __restrict__ src, const int* __restrict__ dst,
                                 const float* __restrict__ ew, const float* __restrict__ dinv,
                                 int* __restrict__ cur, int* __restrict__ srcp,
                                 bf16* __restrict__ normp, int ne)
{
    int e = blockIdx.x * 256 + threadIdx.x;
    if (e >= ne) return;
    int d = dst[e], s = src[e];
    int pos = atomicAdd(&cur[d], 1);
    srcp[pos]  = s;
    normp[pos] = __float2bfloat16(dinv[s] * ew[e] * dinv[d]);
}
__global__ void zint2_kernel(int* __restrict__ p, int* __restrict__ gc, int n)
{
    int t = blockIdx.x * 256 + threadIdx.x;
    if (t < n) p[t] = 0;
    if (t == 0) gc[0] = 0;
}
__global__ void cnt_idx_kernel(const int* __restrict__ idx, int* __restrict__ cnt, int n)
{
    int j = blockIdx.x * 256 + threadIdx.x;
    if (j < n) atomicAdd(&cnt[idx[j]], 1);
}
__global__ void fill_idx_kernel(const int* __restrict__ idx, int* __restrict__ cur,
                                int* __restrict__ jp, int n)
{
    int j = blockIdx.x * 256 + threadIdx.x;
    if (j >= n) return;
    int pos = atomicAdd(&cur[idx[j]], 1);
    jp[pos] = j;
}

// ---- Fused conv v6 (R7-proven best, 123 us @ scale-0): 256-thread blocks, 4 waves share
//      one LDS W-mirror; 8-deep gather ILP; 16-lane group owns 4 whole nodes.
//      NOTE (R9 measured): raising occupancy via 512-thread blocks AMPLIFIES HBM writes
//      2.6x (partial-line writebacks under L2 pressure, WRITE 160->418 MB) and regresses
//      123->204 us. 4 blocks/CU is the measured optimum of this structure. ----
__global__ __launch_bounds__(256, 4)
void fused_conv_kernel(const int* __restrict__ base,
                       const int* __restrict__ srcp, const bf16* __restrict__ normp,
                       const bf16* __restrict__ h_in, bf16* __restrict__ h_out,
                       const float* __restrict__ dinv,
                       const float* __restrict__ W, int woff,
                       const float* __restrict__ bias, int boff,
                       const float* __restrict__ filt, int foff,
                       int first, int store_h, float* __restrict__ acc,
                       int nn, int ne)
{
    __shared__ float sb[4][16 * 68];     // per-wave g-tile [16 nodes][64 pad 68]  (17408 B)
    __shared__ unsigned sW[64 * 65];     // W fragments, lane-major stride-65 u32 (16640 B)
    const int lane = threadIdx.x & 63;
    const int slot = threadIdx.x >> 6;
    const int r = lane & 15, g4 = lane >> 4;
    const int wid  = blockIdx.x * (blockDim.x >> 6) + slot;
    const int nw   = gridDim.x * (blockDim.x >> 6);

    // wave 0 packs W once for the whole block
    if (slot == 0) {
        unsigned* dstw = sW + lane * 65;
#pragma unroll
        for (int s = 0; s < 2; s++)
#pragma unroll
            for (int nb = 0; nb < 4; nb++) {
                bf16x8 bh, bl;
                pack_b8(W + woff, 64, s * 32 + g4 * 8, nb * 16 + r, 64, bh, bl);
                const int f = s * 4 + nb;
                uint4 uh = *(uint4*)&bh;
                uint4 ul = *(uint4*)&bl;
                dstw[f * 4 + 0] = uh.x; dstw[f * 4 + 1] = uh.y;
                dstw[f * 4 + 2] = uh.z; dstw[f * 4 + 3] = uh.w;
                dstw[32 + f * 4 + 0] = ul.x; dstw[32 + f * 4 + 1] = ul.y;
                dstw[32 + f * 4 + 2] = ul.z; dstw[32 + f * 4 + 3] = ul.w;
            }
    }
    __syncthreads();

    float bc[4];
#pragma unroll
    for (int nb = 0; nb < 4; nb++) bc[nb] = bias[boff + nb * 16 + r];
    const float fc = filt[foff];
    float* sbrow = sb[slot];
    const unsigned* myW = sW + lane * 65;
    const int ngrp = (nn + 15) >> 4;

    for (int grp = wid; grp < ngrp; grp += nw) {
        const int n0 = grp << 4;
        int rpl = 0;
        if (lane <= 16) rpl = (n0 + lane < nn) ? base[n0 + lane] : ne;
        // group g4 owns nodes [b4, b4+4); its 5 rowptrs hoisted to regs (full-exec shfl)
        const int b4 = g4 << 2;
        const int q0 = __shfl(rpl, b4);
        const int q1 = __shfl(rpl, b4 + 1);
        const int q2 = __shfl(rpl, b4 + 2);
        const int q3 = __shfl(rpl, b4 + 3);
        const int q4 = __shfl(rpl, b4 + 4);

        int   curl  = 0;                 // local node 0..3; row = b4+curl, single writer
        int   rnext = q1;
        float g0 = 0.f, g1 = 0.f, g2 = 0.f, g3 = 0.f;   // features 4r..4r+3
        auto flush = [&]() {             // plain b128 write; rnext from regs (no shfl)
            *(float4*)(sbrow + (b4 + curl) * 68 + (r << 2)) = make_float4(g0, g1, g2, g3);
            g0 = g1 = g2 = g3 = 0.f;
            curl++;
            rnext = (curl == 1) ? q2 : (curl == 2) ? q3 : (curl == 3) ? q4 : 0x7fffffff;
        };

        for (int eb = q0; eb < q4; eb += 16) {
            const int ei_ = min(eb + r, q4 - 1);           // clamped batch of (src, norm)
            int   sv = srcp[ei_];
            float nv = (eb + r < q4) ? b2f(normp[ei_]) : 0.f;
#pragma unroll
            for (int t = 0; t < 16; t += 8) {              // 8 edges in flight per group
                const int bidx = (g4 << 4) + t;
                int ss[8]; float mm[8]; uint2 pp[8];
#pragma unroll
                for (int j = 0; j < 8; j++) {
                    ss[j] = __shfl(sv, bidx + j);
                    mm[j] = __shfl(nv, bidx + j);
                }
#pragma unroll
                for (int j = 0; j < 8; j++)
                    pp[j] = *(const uint2*)(h_in + ((size_t)ss[j] << 6) + (r << 2));
#pragma unroll
                for (int j = 0; j < 8; j++) {              // consume + boundary flush
                    while (eb + t + j >= rnext) flush();   // flush-before-accumulate (v3-proven)
                    g0 += mm[j] * bflo(pp[j].x); g1 += mm[j] * bfhi(pp[j].x);
                    g2 += mm[j] * bflo(pp[j].y); g3 += mm[j] * bfhi(pp[j].y);
                }
            }
        }
        while (curl < 4) flush();        // remaining partial + zero rows (every row written once)
        __builtin_amdgcn_wave_barrier();

        // self-loop term, vectorized: lane (r,g4) -> node r, features [g4*16, g4*16+16)
        {
            const int node = n0 + r;
            const int ncl = min(node, nn - 1);
            float di = dinv[ncl];
            di = (node < nn) ? di * di : 0.f;
            float* rowp = sbrow + r * 68 + (g4 << 4);
#pragma unroll
            for (int hh = 0; hh < 2; hh++) {
                uint4 hv = *(const uint4*)(h_in + ((size_t)ncl << 6) + (g4 << 4) + hh * 8);
                float4 f0 = *(float4*)(rowp + hh * 8);
                float4 f1 = *(float4*)(rowp + hh * 8 + 4);
                f0.x += di * bflo(hv.x); f0.y += di * bfhi(hv.x);
                f0.z += di * bflo(hv.y); f0.w += di * bfhi(hv.y);
                f1.x += di * bflo(hv.z); f1.y += di * bfhi(hv.z);
                f1.z += di * bflo(hv.w); f1.w += di * bfhi(hv.w);
                *(float4*)(rowp + hh * 8)     = f0;
                *(float4*)(rowp + hh * 8 + 4) = f1;
            }
        }
        __builtin_amdgcn_wave_barrier();

        const int nv16 = min(16, nn - n0);
        f32x4 C[4];
#pragma unroll
        for (int nb = 0; nb < 4; nb++) C[nb] = (f32x4){bc[nb], bc[nb], bc[nb], bc[nb]};
#pragma unroll
        for (int s = 0; s < 2; s++) {
            bf16x8 ah, al;
            pack_a8(sbrow + r * 68 + s * 32 + g4 * 8, ah, al);
#pragma unroll
            for (int nb = 0; nb < 4; nb++) {
                const int f = s * 4 + nb;
                uint4 uh = *(const uint4*)(myW + f * 4);        // ds_read_b128, 2-way = free
                uint4 ul = *(const uint4*)(myW + 32 + f * 4);
                bf16x8 bh = *(bf16x8*)&uh;
                bf16x8 bl = *(bf16x8*)&ul;
                C[nb] = mfma16(ah, bh, C[nb]);
                C[nb] = mfma16(ah, bl, C[nb]);
                C[nb] = mfma16(al, bh, C[nb]);
            }
        }
#pragma unroll
        for (int nb = 0; nb < 4; nb++)
#pragma unroll
            for (int q = 0; q < 4; q++) {
                const int row = g4 * 4 + q;
                if (row < nv16) {
                    const float sv_ = C[nb][q];
                    const float e = __expf(2.f * sv_);
                    const float h = 1.f - 2.f * __builtin_amdgcn_rcpf(e + 1.f);
                    const size_t ai = (size_t)(n0 + row) * 64 + nb * 16 + r;
                    if (store_h) h_out[ai] = __float2bfloat16(h);
                    acc[ai] = (first ? 0.f : acc[ai]) + fc * h;
                }
            }
        __builtin_amdgcn_wave_barrier();
    }
}

// ---------------- pooling gather (R7-proven) ----------------
__global__ void pool_gather_kernel(const int* __restrict__ base, const int* __restrict__ cnt,
                                   const int* __restrict__ jp, const float* __restrict__ accc,
                                   float* __restrict__ fin, int nn)
{
    const int lane = threadIdx.x & 63;
    const int n = blockIdx.x * (blockDim.x >> 6) + (threadIdx.x >> 6);
    if (n >= nn) return;
    const int m = cnt[n];
    if (m == 0) return;
    const int bs = base[n];
    float s = 0.f;
    for (int t = bs; t < bs + m; t++) {
        int j = jp[t];
        s += accc[(size_t)j * 64 + lane];
    }
    fin[(size_t)n * 64 + lane] += s / (float)m;
}

// ---------------- Decoder: layer1 MFMA, layer2 shuffle-reduce ----------------
__global__ __launch_bounds__(256, 3)
void dec_kernel(const float* __restrict__ fin,
                const float* __restrict__ W1, const float* __restrict__ b1,
                const float* __restrict__ W2, const float* __restrict__ b2,
                const float* __restrict__ pa, float* __restrict__ out, int nn)
{
    const int lane = threadIdx.x & 63;
    const int r = lane & 15, g4 = lane >> 4;
    const int wid = blockIdx.x * (blockDim.x >> 6) + (threadIdx.x >> 6);
    const int nw  = gridDim.x * (blockDim.x >> 6);

    bf16x8 Wh[2][4], Wl[2][4];
#pragma unroll
    for (int s = 0; s < 2; s++)
#pragma unroll
        for (int nb = 0; nb < 4; nb++)
            pack_b8(W1, 64, s * 32 + g4 * 8, nb * 16 + r, 64, Wh[s][nb], Wl[s][nb]);
    float bc[4], w20[4], w21[4];
#pragma unroll
    for (int nb = 0; nb < 4; nb++) {
        bc[nb]  = b1[nb * 16 + r];
        w20[nb] = W2[(nb * 16 + r) * 2 + 0];
        w21[nb] = W2[(nb * 16 + r) * 2 + 1];
    }
    const float bb20 = b2[0], bb21 = b2[1];
    const float a = pa[0];
    const int ntile = (nn + 15) >> 4;

    for (int tt = wid; tt < ntile; tt += nw) {
        const int n0 = tt << 4;
        f32x4 C[4];
#pragma unroll
        for (int nb = 0; nb < 4; nb++) C[nb] = (f32x4){bc[nb], bc[nb], bc[nb], bc[nb]};
#pragma unroll
        for (int s = 0; s < 2; s++) {
            bf16x8 ah, al;
            pack_a8(fin + (size_t)(n0 + r) * 64 + s * 32 + g4 * 8, ah, al);
#pragma unroll
            for (int nb = 0; nb < 4; nb++) {
                C[nb] = mfma16(ah, Wh[s][nb], C[nb]);
                C[nb] = mfma16(ah, Wl[s][nb], C[nb]);
                C[nb] = mfma16(al, Wh[s][nb], C[nb]);
            }
        }
#pragma unroll
        for (int q = 0; q < 4; q++) {
            float p0 = 0.f, p1 = 0.f;
#pragma unroll
            for (int nb = 0; nb < 4; nb++) {
                float y = C[nb][q];
                y = y > 0.f ? y : a * y;
                p0 += y * w20[nb]; p1 += y * w21[nb];
            }
            p0 += __shfl_xor(p0, 1); p1 += __shfl_xor(p1, 1);
            p0 += __shfl_xor(p0, 2); p1 += __shfl_xor(p1, 2);
            p0 += __shfl_xor(p0, 4); p1 += __shfl_xor(p1, 4);
            p0 += __shfl_xor(p0, 8); p1 += __shfl_xor(p1, 8);
            if (r == 0) {
                const int node = n0 + g4 * 4 + q;
                if (node < nn) {
                    float o0 = p0 + bb20; o0 = o0 > 0.f ? o0 : a * o0;
                    float o1 = p1 + bb21; o1 = o1 > 0.f ? o1 : a * o1;
                    ((float2*)out)[node] = make_float2(o0, o1);
                }
            }
        }
    }
}

extern "C" void kernel_launch(void* const* d_in, const int* in_sizes, int n_in,
                              void* d_out, int out_size, void* d_ws, size_t ws_size,
                              hipStream_t stream)
{
    const float* stat = (const float*)d_in[0];
    const float* dyn  = (const float*)d_in[1];
    const int*   ei[3]   = {(const int*)d_in[2], (const int*)d_in[4], (const int*)d_in[6]};
    const float* ea[3]   = {(const float*)d_in[3], (const float*)d_in[5], (const float*)d_in[7]};
    const int*   pidx[2] = {(const int*)d_in[8], (const int*)d_in[9]};
    const float* encW1 = (const float*)d_in[10]; const float* encb1 = (const float*)d_in[11];
    const float* encW2 = (const float*)d_in[12]; const float* encb2 = (const float*)d_in[13];
    const float* encpa = (const float*)d_in[14];
    const float* gW    = (const float*)d_in[15]; const float* gbias = (const float*)d_in[16];
    const float* filt  = (const float*)d_in[17];
    const float* dW1   = (const float*)d_in[18]; const float* db1   = (const float*)d_in[19];
    const float* dW2   = (const float*)d_in[20]; const float* db2   = (const float*)d_in[21];
    const float* dpa   = (const float*)d_in[22];

    auto al = [](size_t x) { return (x + 255) & ~(size_t)255; };
    char* w = (char*)d_ws;
    size_t off = 0;
    bf16* X    = (bf16*)(w + off); off += al((size_t)cNTOT * 64 * 2);   // 67.2 MB
    bf16* HB   = (bf16*)(w + off); off += al((size_t)cN0 * 64 * 2);     // 51.2 MB
    float* FIN = (float*)(w + off); off += al((size_t)cN0 * 64 * 4);    // 102.4 MB
    float* ACCC= (float*)(w + off); off += al((size_t)cN1 * 64 * 4);    // 25.6 MB
    float* DINV= (float*)(w + off); off += al((size_t)cN0 * 4);
    int* CNTI  = (int*)(w + off);  off += al((size_t)cN0 * 4);
    int* BASE  = (int*)(w + off);  off += al((size_t)cN0 * 4);
    int* CUR   = (int*)(w + off);  off += al((size_t)cN0 * 4);
    int* SRCP  = (int*)(w + off);  off += al((size_t)cE0 * 4);
    bf16* NORMP= (bf16*)(w + off); off += al((size_t)cE0 * 2);
    int* JP    = (int*)(w + off);  off += al((size_t)cN1 * 4);
    int* GC    = (int*)(w + off);  off += 256;
    int* BSUM  = (int*)(w + off);  off += al((size_t)2048 * 4);         // == R4's proven ~263 MB
    // DC (u64[cN0] = 3.2 MB) ALIASES ACCC (25.6 MB): DC is consumed by scan_blk before any
    // conv writes ACCC (first=1 full overwrite), and each scale's pool_gather drains ACCC
    // before the next scale's zdc. Stream-ordered, zero extra workspace.
    u64* DC    = (u64*)ACCC;

    const int Ns[3]  = {cN0, cN1, cN2};
    const int Es[3]  = {cE0, cE1, cE2};
    const int ptr[3] = {0, cN0, cN0 + cN1};
#define NB(x) (((x) + 255) / 256)

    enc_kernel<<<4096, 256, 0, stream>>>(stat, dyn, encW1, encb1, encW2, encb2, encpa, X, cNTOT);

    for (int i = 0; i < 3; i++) {
        const int* srcp_in = ei[i];
        const int* dstp    = ei[i] + Es[i];
        zdc_kernel      <<<NB(Ns[i]), 256, 0, stream>>>(DC, Ns[i]);
        edge_pack_kernel<<<NB(Es[i]), 256, 0, stream>>>(dstp, ea[i], DC, Es[i]);
        scan_blk_kernel <<<NB(Ns[i]), 256, 0, stream>>>(DC, BASE, BSUM, DINV, Ns[i]);
        scan_top_kernel <<<1, 256, 0, stream>>>(BSUM, NB(Ns[i]));
        scan_add_kernel <<<NB(Ns[i]), 256, 0, stream>>>(BASE, BSUM, CUR, Ns[i]);
        fill_edge_kernel<<<NB(Es[i]), 256, 0, stream>>>(srcp_in, dstp, ea[i], DINV, CUR, SRCP, NORMP, Es[i]);

        bf16* ping = X + (size_t)ptr[i] * 64;
        bf16* pong = HB;
        float* acc_i = (i == 0) ? FIN : ACCC;
        const int ngrp = (Ns[i] + 15) / 16;
        const int cblk = max(1, min(4096, (ngrp + 3) / 4));
        for (int k = 0; k < 3; k++) {
            bf16* hin  = (k & 1) ? pong : ping;
            bf16* hout = (k & 1) ? ping : pong;
            fused_conv_kernel<<<cblk, 256, 0, stream>>>(BASE, SRCP, NORMP,
                hin, hout, DINV, gW, i * 4096, gbias, i * 64,
                filt, i * 3 + k, (k == 0) ? 1 : 0, (k < 2) ? 1 : 0, acc_i, Ns[i], Es[i]);
        }
        if (i >= 1) {
            int nj = (i == 1) ? cN1 : cN2;
            const int* pp = pidx[i - 1];
            zint2_kernel   <<<NB(cN0), 256, 0, stream>>>(CNTI, GC, cN0);
            cnt_idx_kernel <<<NB(nj), 256, 0, stream>>>(pp, CNTI, nj);
            grab_kernel    <<<NB(cN0), 256, 0, stream>>>(CNTI, BASE, CUR, GC, cN0);
            fill_idx_kernel<<<NB(nj), 256, 0, stream>>>(pp, CUR, JP, nj);
            pool_gather_kernel<<<(cN0 + 3) / 4, 256, 0, stream>>>(BASE, CNTI, JP, ACCC, FIN, cN0);
        }
    }
    dec_kernel<<<4096, 256, 0, stream>>>(FIN, dW1, db1, dW2, db2, dpa, (float*)d_out, cN0);
#undef NB
}